// Round 12
// baseline (4222.331 us; speedup 1.0000x reference)
//
#include <hip/hip_runtime.h>
#include <cstdint>
#include <cmath>

typedef unsigned short u16;
typedef unsigned int u32;
typedef short bf16x8 __attribute__((ext_vector_type(8)));
typedef float f32x4 __attribute__((ext_vector_type(4)));

#define DEV static __device__ __forceinline__

DEV u16 f2bf(float f) {
  union { float f; u32 u; } v; v.f = f;
  return (u16)((v.u + 0x7FFFu + ((v.u >> 16) & 1u)) >> 16);
}
DEV float bf2f(u32 lo16) {
  union { u32 u; float f; } v; v.u = lo16 << 16; return v.f;
}

DEV void gload16(const void* g, u16* l) {
  __builtin_amdgcn_global_load_lds(
      (const __attribute__((address_space(1))) void*)g,
      (__attribute__((address_space(3))) void*)l, 16, 0, 0);
}

// ---------------------------------------------------------------------------
// gemmG: 256x128 bf16 GEMM, 8 waves x (64x64 out), BK=64, single-buffer
// 48 KiB LDS, T2 swizzle (0-conflict class), plain block order.
// (r10 best-measured config for QKV / MLP1.)
// MODE 3: bf16 = tanh-gelu(v+bias) | MODE 5: QKV split (QK bf16 / Vt store)
// ---------------------------------------------------------------------------
template<int MODE>
__global__ __launch_bounds__(512, 4)
void gemmG(const u16* __restrict__ A, const u16* __restrict__ Bt,
           void* __restrict__ Cv, const float* __restrict__ bias,
           u16* __restrict__ Vt, int M, int N, int K, int ldA, int ldB,
           float scale)
{
  __shared__ __align__(16) u16 As[256 * 64];   // 32 KiB
  __shared__ __align__(16) u16 Bs[128 * 64];   // 16 KiB

  const long m0 = (long)blockIdx.x * 256, n0 = (long)blockIdx.y * 128;
  const int t = threadIdx.x;
  const int wave = t >> 6, lane = t & 63;
  const int wr = (wave >> 1) * 64, wc = (wave & 1) * 64;   // 4(M) x 2(N)
  const int lg = lane >> 4, lr = lane & 15;

  const long ldA2 = (long)ldA * 2, ldB2 = (long)ldB * 2;

  const int rl = lane >> 3, c7 = lane & 7;
  const int sb = (c7 * 16) ^ (rl << 4);
  const char* aP[4]; const char* bP[2];
  u16* aL[4]; u16* bL[2];
  {
    const char* Ab = (const char*)A;
    const char* Bb = (const char*)Bt;
    #pragma unroll
    for (int c = 0; c < 4; ++c) {
      const int q = c * 8 + wave;
      aP[c] = Ab + (m0 + q * 8 + rl) * ldA2 + sb;
      aL[c] = As + q * 512;
    }
    #pragma unroll
    for (int c = 0; c < 2; ++c) {
      const int q = c * 8 + wave;
      bP[c] = Bb + (n0 + q * 8 + rl) * ldB2 + sb;
      bL[c] = Bs + q * 512;
    }
  }

  const int rswz = (lr & 7) << 4;
  auto rd = [&](const u16* base, int row, int cbyte) -> bf16x8 {
    return *reinterpret_cast<const bf16x8*>(
        reinterpret_cast<const char*>(base) + row * 128 + (cbyte ^ rswz));
  };

  f32x4 acc[4][4];
  #pragma unroll
  for (int i = 0; i < 4; ++i)
    #pragma unroll
    for (int j = 0; j < 4; ++j)
      acc[i][j] = (f32x4){0.f, 0.f, 0.f, 0.f};

  for (int k0 = 0; k0 < K; k0 += 64) {
    #pragma unroll
    for (int c = 0; c < 4; ++c) { gload16(aP[c], aL[c]); aP[c] += 128; }
    #pragma unroll
    for (int c = 0; c < 2; ++c) { gload16(bP[c], bL[c]); bP[c] += 128; }
    __syncthreads();

    #pragma unroll
    for (int ks = 0; ks < 2; ++ks) {
      bf16x8 a[4], b[4];
      #pragma unroll
      for (int i = 0; i < 4; ++i)
        a[i] = rd(As, wr + i * 16 + lr, ks * 64 + lg * 16);
      #pragma unroll
      for (int i = 0; i < 4; ++i)
        b[i] = rd(Bs, wc + i * 16 + lr, ks * 64 + lg * 16);
      #pragma unroll
      for (int mi = 0; mi < 4; ++mi)
        #pragma unroll
        for (int ni = 0; ni < 4; ++ni)
          acc[mi][ni] = __builtin_amdgcn_mfma_f32_16x16x32_bf16(a[mi], b[ni], acc[mi][ni], 0, 0, 0);
    }
    __syncthreads();
  }

  #pragma unroll
  for (int mi = 0; mi < 4; ++mi) {
    #pragma unroll
    for (int ni = 0; ni < 4; ++ni) {
      #pragma unroll
      for (int r = 0; r < 4; ++r) {
        const long grow = m0 + wr + mi * 16 + lg * 4 + r;
        const long gcol = n0 + wc + ni * 16 + lr;
        const float v = acc[mi][ni][r];
        if constexpr (MODE == 3) {
          const float x = v + bias[gcol];
          const float u2 = 1.59576912f * x * (1.f + 0.044715f * x * x);
          const float ge = x / (1.f + __expf(-u2));
          ((u16*)Cv)[grow * N + gcol] = f2bf(ge);
        } else if constexpr (MODE == 5) {
          if (gcol < 2048) {
            ((u16*)Cv)[grow * 2048 + gcol] = f2bf(v * scale);
          } else {
            const long b = grow >> 10, tk = grow & 1023, d = gcol - 2048;
            Vt[(b << 20) + (d << 10) + tk] = f2bf(v);
          }
        }
      }
    }
  }
}

// ---------------------------------------------------------------------------
// gemm8: 8-wave 128x128, BK=64, single-buffer 32 KiB (4 blocks/CU capable;
// the r7/r9/r10-proven high-TLP config). MODE 4: f32 += v + bias
// ---------------------------------------------------------------------------
template<int MODE>
__global__ __launch_bounds__(512, 4)
void gemm8(const u16* __restrict__ A, const u16* __restrict__ Bt,
           void* __restrict__ Cv, const float* __restrict__ bias,
           u16* __restrict__ Vt, int M, int N, int K, int ldA, int ldB,
           float scale)
{
  __shared__ __align__(16) u16 As[128 * 64];
  __shared__ __align__(16) u16 Bs[128 * 64];

  const long m0 = (long)blockIdx.x * 128, n0 = (long)blockIdx.y * 128;
  const int t = threadIdx.x;
  const int wave = t >> 6, lane = t & 63;
  const int wr = (wave >> 2) * 64, wc = (wave & 3) * 32;
  const int lg = lane >> 4, lr = lane & 15;

  const long ldA2 = (long)ldA * 2, ldB2 = (long)ldB * 2;

  const int rl = lane >> 3, c7 = lane & 7;
  const int sb = (c7 * 16) ^ (rl << 4);
  const char* aP[2]; const char* bP[2];
  u16* aL[2]; u16* bL[2];
  {
    const char* Ab = (const char*)A;
    const char* Bb = (const char*)Bt;
    #pragma unroll
    for (int c = 0; c < 2; ++c) {
      const int q = c * 8 + wave;
      aP[c] = Ab + (m0 + q * 8 + rl) * ldA2 + sb;
      bP[c] = Bb + (n0 + q * 8 + rl) * ldB2 + sb;
      aL[c] = As + q * 512;
      bL[c] = Bs + q * 512;
    }
  }

  const int rswz = (lr & 7) << 4;
  auto rd = [&](const u16* base, int row, int cbyte) -> bf16x8 {
    return *reinterpret_cast<const bf16x8*>(
        reinterpret_cast<const char*>(base) + row * 128 + (cbyte ^ rswz));
  };

  f32x4 acc[4][2];
  #pragma unroll
  for (int i = 0; i < 4; ++i)
    #pragma unroll
    for (int j = 0; j < 2; ++j)
      acc[i][j] = (f32x4){0.f, 0.f, 0.f, 0.f};

  for (int k0 = 0; k0 < K; k0 += 64) {
    #pragma unroll
    for (int c = 0; c < 2; ++c) {
      gload16(aP[c], aL[c]);
      gload16(bP[c], bL[c]);
      aP[c] += 128; bP[c] += 128;
    }
    __syncthreads();

    #pragma unroll
    for (int ks = 0; ks < 2; ++ks) {
      bf16x8 a[4], b[2];
      #pragma unroll
      for (int i = 0; i < 4; ++i)
        a[i] = rd(As, wr + i * 16 + lr, ks * 64 + lg * 16);
      #pragma unroll
      for (int i = 0; i < 2; ++i)
        b[i] = rd(Bs, wc + i * 16 + lr, ks * 64 + lg * 16);
      #pragma unroll
      for (int mi = 0; mi < 4; ++mi)
        #pragma unroll
        for (int ni = 0; ni < 2; ++ni)
          acc[mi][ni] = __builtin_amdgcn_mfma_f32_16x16x32_bf16(a[mi], b[ni], acc[mi][ni], 0, 0, 0);
    }
    __syncthreads();
  }

  #pragma unroll
  for (int mi = 0; mi < 4; ++mi) {
    #pragma unroll
    for (int ni = 0; ni < 2; ++ni) {
      #pragma unroll
      for (int r = 0; r < 4; ++r) {
        const long grow = m0 + wr + mi * 16 + lg * 4 + r;
        const long gcol = n0 + wc + ni * 16 + lr;
        const float v = acc[mi][ni][r];
        if constexpr (MODE == 4) {
          float* Cp = (float*)Cv;
          const long idx = grow * N + gcol;
          Cp[idx] = Cp[idx] + v + bias[gcol];
        }
      }
    }
  }
}

// ---------------------------------------------------------------------------
// gemm8b: batched 8-wave 128x128, BK=64, single-buffer (S and PV).
// MODE 0: bf16 = v*scale | MODE 2: f32 +=
// ---------------------------------------------------------------------------
template<int MODE>
__global__ __launch_bounds__(512, 4)
void gemm8b(const u16* __restrict__ A, const u16* __restrict__ Bt,
            void* __restrict__ Cv, int N, int K, int ldA, int ldB,
            long sA, long sB, long sC, float scale)
{
  __shared__ __align__(16) u16 As[128 * 64];
  __shared__ __align__(16) u16 Bs[128 * 64];

  const int bz = blockIdx.z;
  const long m0 = (long)blockIdx.x * 128, n0 = (long)blockIdx.y * 128;
  const int t = threadIdx.x;
  const int wave = t >> 6, lane = t & 63;
  const int wr = (wave >> 2) * 64, wc = (wave & 3) * 32;
  const int lg = lane >> 4, lr = lane & 15;

  const long ldA2 = (long)ldA * 2, ldB2 = (long)ldB * 2;

  const int rl = lane >> 3, c7 = lane & 7;
  const int sb = (c7 * 16) ^ (rl << 4);
  const char* aP[2]; const char* bP[2];
  u16* aL[2]; u16* bL[2];
  {
    const char* Ab = (const char*)(A + (long)bz * sA);
    const char* Bb = (const char*)(Bt + (long)bz * sB);
    #pragma unroll
    for (int c = 0; c < 2; ++c) {
      const int q = c * 8 + wave;
      aP[c] = Ab + (m0 + q * 8 + rl) * ldA2 + sb;
      bP[c] = Bb + (n0 + q * 8 + rl) * ldB2 + sb;
      aL[c] = As + q * 512;
      bL[c] = Bs + q * 512;
    }
  }

  const int rswz = (lr & 7) << 4;
  auto rd = [&](const u16* base, int row, int cbyte) -> bf16x8 {
    return *reinterpret_cast<const bf16x8*>(
        reinterpret_cast<const char*>(base) + row * 128 + (cbyte ^ rswz));
  };

  f32x4 acc[4][2];
  #pragma unroll
  for (int i = 0; i < 4; ++i)
    #pragma unroll
    for (int j = 0; j < 2; ++j)
      acc[i][j] = (f32x4){0.f, 0.f, 0.f, 0.f};

  for (int k0 = 0; k0 < K; k0 += 64) {
    #pragma unroll
    for (int c = 0; c < 2; ++c) {
      gload16(aP[c], aL[c]);
      gload16(bP[c], bL[c]);
      aP[c] += 128; bP[c] += 128;
    }
    __syncthreads();

    #pragma unroll
    for (int ks = 0; ks < 2; ++ks) {
      bf16x8 a[4], b[2];
      #pragma unroll
      for (int i = 0; i < 4; ++i)
        a[i] = rd(As, wr + i * 16 + lr, ks * 64 + lg * 16);
      #pragma unroll
      for (int i = 0; i < 2; ++i)
        b[i] = rd(Bs, wc + i * 16 + lr, ks * 64 + lg * 16);
      #pragma unroll
      for (int mi = 0; mi < 4; ++mi)
        #pragma unroll
        for (int ni = 0; ni < 2; ++ni)
          acc[mi][ni] = __builtin_amdgcn_mfma_f32_16x16x32_bf16(a[mi], b[ni], acc[mi][ni], 0, 0, 0);
    }
    __syncthreads();
  }

  #pragma unroll
  for (int mi = 0; mi < 4; ++mi) {
    #pragma unroll
    for (int ni = 0; ni < 2; ++ni) {
      #pragma unroll
      for (int r = 0; r < 4; ++r) {
        const long grow = m0 + wr + mi * 16 + lg * 4 + r;
        const long gcol = n0 + wc + ni * 16 + lr;
        const float v = acc[mi][ni][r];
        if constexpr (MODE == 0) {
          u16* Cp = (u16*)Cv + (long)bz * sC;
          Cp[grow * N + gcol] = f2bf(v * scale);
        } else if constexpr (MODE == 2) {
          float* Cp = (float*)Cv + (long)bz * sC;
          Cp[grow * N + gcol] += v;
        }
      }
    }
  }
}

// ---------------------------------------------------------------------------
// trans_all: ALL 12 layers' weight transpose+convert in ONE launch.
// Grid = 12 * 2816 blocks; block b -> layer l = b/2816, sub bb = b%2816.
// Per-layer output (u16 units, stride LW = 11*1048576): WqT+0, WkT+1M,
// WvT+2M (=> QKV concat [3072][1024]), W1T+3M, W2T+7M.
// ---------------------------------------------------------------------------
__global__ __launch_bounds__(256)
void trans_all(const float* __restrict__ Wq, const float* __restrict__ Wk,
               const float* __restrict__ Wv, const float* __restrict__ w1,
               const float* __restrict__ w2, u16* __restrict__ oball)
{
  __shared__ u16 T[64][68];
  const int l = blockIdx.x / 2816;
  const int b = blockIdx.x % 2816;
  const long s1M = 1048576L;
  u16* ob = oball + (long)l * (11L * s1M);

  const float* in; u16* out; int K, N, tk, tn;
  if (b < 768) {
    const int m = b >> 8, tt = b & 255;
    in = ((m == 0) ? Wq : (m == 1) ? Wk : Wv) + (long)l * s1M;
    out = ob + (long)m * s1M;
    K = 1024; N = 1024; tk = tt >> 4; tn = tt & 15;
  } else if (b < 1792) {
    const int tt = b - 768;
    in = w1 + (long)l * 4L * s1M; out = ob + 3L * s1M; K = 1024; N = 4096;
    tk = tt >> 6; tn = tt & 63;
  } else {
    const int tt = b - 1792;
    in = w2 + (long)l * 4L * s1M; out = ob + 7L * s1M; K = 4096; N = 1024;
    tk = tt >> 4; tn = tt & 15;
  }
  const int k0 = tk * 64, n0 = tn * 64;
  const int t = threadIdx.x;
  {
    const int r = t >> 2, cq = (t & 3) * 16;
    const float* src = in + (long)(k0 + r) * N + n0 + cq;
    #pragma unroll
    for (int q = 0; q < 4; ++q) {
      const float4 v = *reinterpret_cast<const float4*>(src + q * 4);
      T[r][cq + q * 4 + 0] = f2bf(v.x);
      T[r][cq + q * 4 + 1] = f2bf(v.y);
      T[r][cq + q * 4 + 2] = f2bf(v.z);
      T[r][cq + q * 4 + 3] = f2bf(v.w);
    }
  }
  __syncthreads();
  {
    const int n = t >> 2, kq2 = (t & 3) * 16;
    u16 tmp[16];
    #pragma unroll
    for (int j = 0; j < 16; ++j) tmp[j] = T[kq2 + j][n];
    uint4* dst = reinterpret_cast<uint4*>(out + (long)(n0 + n) * K + k0 + kq2);
    dst[0] = *reinterpret_cast<const uint4*>(&tmp[0]);
    dst[1] = *reinterpret_cast<const uint4*>(&tmp[8]);
  }
}

// ---------------------------------------------------------------------------
__global__ __launch_bounds__(256)
void embed_k(const int* __restrict__ xt, const int* __restrict__ zi,
             const float* __restrict__ pos, const float* __restrict__ temb,
             float* __restrict__ H)
{
  const int bt = blockIdx.x;
  const int b = bt >> 10, tk = bt & 1023;
  const int d = threadIdx.x * 4;
  const float4 p = reinterpret_cast<const float4*>(pos + (long)tk * 1024)[threadIdx.x];
  float4 v;
  if (tk < 512) {
    const float z = (float)zi[b * 512 + tk];
    const float c0 = (float)(d + 0) - z, c1 = (float)(d + 1) - z;
    const float c2 = (float)(d + 2) - z, c3 = (float)(d + 3) - z;
    v.x = (d + 0 < 10) ? -0.5f * c0 * c0 : 0.f;
    v.y = (d + 1 < 10) ? -0.5f * c1 * c1 : 0.f;
    v.z = (d + 2 < 10) ? -0.5f * c2 * c2 : 0.f;
    v.w = (d + 3 < 10) ? -0.5f * c3 * c3 : 0.f;
  } else {
    const float* te = temb + (long)xt[b * 512 + (tk - 512)] * 1024;
    v = reinterpret_cast<const float4*>(te)[threadIdx.x];
  }
  float4 o; o.x = v.x + p.x; o.y = v.y + p.y; o.z = v.z + p.z; o.w = v.w + p.w;
  reinterpret_cast<float4*>(H + (long)bt * 1024)[threadIdx.x] = o;
}

__global__ __launch_bounds__(256)
void ln_k(const float* __restrict__ X, const float* __restrict__ g,
          const float* __restrict__ bta, u16* __restrict__ Y)
{
  __shared__ float sm[8];
  const long row = blockIdx.x;
  const float4 x = reinterpret_cast<const float4*>(X + row * 1024)[threadIdx.x];
  float s1 = x.x + x.y + x.z + x.w;
  float s2 = x.x * x.x + x.y * x.y + x.z * x.z + x.w * x.w;
  #pragma unroll
  for (int o = 32; o > 0; o >>= 1) { s1 += __shfl_down(s1, o); s2 += __shfl_down(s2, o); }
  const int w = threadIdx.x >> 6, ln = threadIdx.x & 63;
  if (ln == 0) { sm[w] = s1; sm[4 + w] = s2; }
  __syncthreads();
  s1 = sm[0] + sm[1] + sm[2] + sm[3];
  s2 = sm[4] + sm[5] + sm[6] + sm[7];
  const float mu = s1 * (1.f / 1024.f);
  const float var = s2 * (1.f / 1024.f) - mu * mu;
  const float inv = rsqrtf(var + 1e-5f);
  const float4 gg = reinterpret_cast<const float4*>(g)[threadIdx.x];
  const float4 bb = reinterpret_cast<const float4*>(bta)[threadIdx.x];
  const u32 o0 = (u32)f2bf((x.x - mu) * inv * gg.x + bb.x) | ((u32)f2bf((x.y - mu) * inv * gg.y + bb.y) << 16);
  const u32 o1 = (u32)f2bf((x.z - mu) * inv * gg.z + bb.z) | ((u32)f2bf((x.w - mu) * inv * gg.w + bb.w) << 16);
  reinterpret_cast<uint2*>(Y + row * 1024)[threadIdx.x] = make_uint2(o0, o1);
}

// Row softmax over 1024 cols, bf16 in -> bf16 out
__global__ __launch_bounds__(256)
void sm_k(const u16* __restrict__ S, u16* __restrict__ P)
{
  __shared__ float sm[8];
  const long row = blockIdx.x;
  const uint2 raw = reinterpret_cast<const uint2*>(S + row * 1024)[threadIdx.x];
  const float x0 = bf2f(raw.x & 0xffffu), x1 = bf2f(raw.x >> 16);
  const float x2 = bf2f(raw.y & 0xffffu), x3 = bf2f(raw.y >> 16);
  float m = fmaxf(fmaxf(x0, x1), fmaxf(x2, x3));
  #pragma unroll
  for (int o = 32; o > 0; o >>= 1) m = fmaxf(m, __shfl_down(m, o));
  const int w = threadIdx.x >> 6, ln = threadIdx.x & 63;
  if (ln == 0) sm[w] = m;
  __syncthreads();
  m = fmaxf(fmaxf(sm[0], sm[1]), fmaxf(sm[2], sm[3]));
  const float e0 = __expf(x0 - m), e1 = __expf(x1 - m);
  const float e2 = __expf(x2 - m), e3 = __expf(x3 - m);
  float s = e0 + e1 + e2 + e3;
  #pragma unroll
  for (int o = 32; o > 0; o >>= 1) s += __shfl_down(s, o);
  if (ln == 0) sm[4 + w] = s;
  __syncthreads();
  const float tot = sm[4] + sm[5] + sm[6] + sm[7];
  const float r = 1.0f / tot;
  const u32 o0 = (u32)f2bf(e0 * r) | ((u32)f2bf(e1 * r) << 16);
  const u32 o1 = (u32)f2bf(e2 * r) | ((u32)f2bf(e3 * r) << 16);
  reinterpret_cast<uint2*>(P + row * 1024)[threadIdx.x] = make_uint2(o0, o1);
}

__global__ __launch_bounds__(256)
void ro_k(const float* __restrict__ H, const float* __restrict__ w,
          const float* __restrict__ b, float* __restrict__ out)
{
  __shared__ float sm[4];
  const int row = blockIdx.x;
  const int bb = row >> 9, i = row & 511;
  const float* h = H + ((long)bb * 1024 + i) * 1024;
  const float4 x = reinterpret_cast<const float4*>(h)[threadIdx.x];
  const float4 ww = reinterpret_cast<const float4*>(w)[threadIdx.x];
  float s = x.x * ww.x + x.y * ww.y + x.z * ww.z + x.w * ww.w;
  #pragma unroll
  for (int o = 32; o > 0; o >>= 1) s += __shfl_down(s, o);
  const int wv = threadIdx.x >> 6, ln = threadIdx.x & 63;
  if (ln == 0) sm[wv] = s;
  __syncthreads();
  if (threadIdx.x == 0) out[row] = sm[0] + sm[1] + sm[2] + sm[3] + b[0];
}

// ---------------------------------------------------------------------------
extern "C" void kernel_launch(void* const* d_in, const int* in_sizes, int n_in,
                              void* d_out, int out_size, void* d_ws, size_t ws_size,
                              hipStream_t stream)
{
  const int* xt = (const int*)d_in[0];
  const int* zi = (const int*)d_in[1];
  const float* pos  = (const float*)d_in[2];
  const float* temb = (const float*)d_in[3];
  const float* Wq = (const float*)d_in[4];
  const float* Wk = (const float*)d_in[5];
  const float* Wv = (const float*)d_in[6];
  const float* ln1g = (const float*)d_in[7];
  const float* ln1b = (const float*)d_in[8];
  const float* ln2g = (const float*)d_in[9];
  const float* ln2b = (const float*)d_in[10];
  const float* w1 = (const float*)d_in[11];
  const float* b1 = (const float*)d_in[12];
  const float* w2 = (const float*)d_in[13];
  const float* b2 = (const float*)d_in[14];
  const float* row_w = (const float*)d_in[15];
  const float* row_b = (const float*)d_in[16];

  char* ws = (char*)d_ws;
  const long MB = 1024 * 1024;
  float* H   = (float*)(ws + 0);          // 32 MB  [8][1024][1024] f32
  u16*   H1  = (u16*)(ws + 32 * MB);      // 16 MB  [8192][1024] bf16
  u16*   QK  = (u16*)(ws + 48 * MB);      // 32 MB  [8192][2048] bf16 (Q||K)
  u16*   Vt  = (u16*)(ws + 80 * MB);      // 16 MB  [8][1024(d)][1024(t)]
  u16*   S   = (u16*)(ws + 96 * MB);      // 16 MB  bf16
  u16*   P   = (u16*)(ws + 112 * MB);     // 16 MB
  u16*   G   = (u16*)(ws + 80 * MB);      // 64 MB, aliases Vt/S/P (dead in MLP)
  u16*   WTall = (u16*)(ws + 160 * MB);   // 264 MB: 12 layers x 22 MB bf16 B^T

  const long s1M = 1024L * 1024L;
  const long s2M = 2L * 1024L * 1024L;
  const long LW  = 11L * s1M;             // per-layer u16 stride in WTall

  // all-layer weight convert/transpose, one launch (ws_size ~805 MB per
  // harness fill; 160+264=424 MB used)
  trans_all<<<12 * 2816, 256, 0, stream>>>(Wq, Wk, Wv, w1, w2, WTall);

  embed_k<<<8192, 256, 0, stream>>>(xt, zi, pos, temb, H);

  for (int l = 0; l < 12; ++l) {
    u16* WT  = WTall + (long)l * LW;
    u16* W1T = WT + 3 * s1M;              // [4096][1024]
    u16* W2T = WT + 7 * s1M;              // [1024][4096]
    const float* mb1 = b1 + (long)l * 4096L;
    const float* mb2 = b2 + (long)l * 1024L;

    ln_k<<<8192, 256, 0, stream>>>(H, ln1g + l * 1024, ln1b + l * 1024, H1);

    // [Q||K||V] = H1 @ [wq||wk||wv]; V third stored transposed into Vt
    gemmG<5><<<dim3(32, 24, 1), 512, 0, stream>>>(H1, WT, QK, nullptr, Vt,
        8192, 3072, 1024, 1024, 1024, 1.f);

    // S = Q @ K^T / 32
    gemm8b<0><<<dim3(8, 8, 8), 512, 0, stream>>>(QK, QK + 1024, S,
        1024, 1024, 2048, 2048, s2M, s2M, s1M, 1.f / 32.f);

    sm_k<<<8192, 256, 0, stream>>>(S, P);

    // H += P @ V
    gemm8b<2><<<dim3(8, 8, 8), 512, 0, stream>>>(P, Vt, (void*)H,
        1024, 1024, 1024, 1024, s1M, s1M, s1M, 1.f);

    ln_k<<<8192, 256, 0, stream>>>(H, ln2g + l * 1024, ln2b + l * 1024, H1);

    // G = gelu(H1 @ w1 + b1)
    gemmG<3><<<dim3(32, 32, 1), 512, 0, stream>>>(H1, W1T, G, mb1, nullptr,
        8192, 4096, 1024, 1024, 1024, 1.f);
    // H += G @ w2 + b2
    gemm8<4><<<dim3(64, 8, 1), 512, 0, stream>>>(G, W2T, (void*)H, mb2, nullptr,
        8192, 1024, 4096, 4096, 4096, 1.f);
  }

  ro_k<<<4096, 256, 0, stream>>>(H, row_w, row_b, (float*)d_out);
}

// Round 13
// 3740.867 us; speedup vs baseline: 1.1287x; 1.1287x over previous
//
#include <hip/hip_runtime.h>
#include <cstdint>
#include <cmath>

typedef unsigned short u16;
typedef unsigned int u32;
typedef short bf16x8 __attribute__((ext_vector_type(8)));
typedef float f32x4 __attribute__((ext_vector_type(4)));

#define DEV static __device__ __forceinline__

DEV u16 f2bf(float f) {
  union { float f; u32 u; } v; v.f = f;
  return (u16)((v.u + 0x7FFFu + ((v.u >> 16) & 1u)) >> 16);
}
DEV float bf2f(u32 lo16) {
  union { u32 u; float f; } v; v.u = lo16 << 16; return v.f;
}

DEV void gload16(const void* g, u16* l) {
  __builtin_amdgcn_global_load_lds(
      (const __attribute__((address_space(1))) void*)g,
      (__attribute__((address_space(3))) void*)l, 16, 0, 0);
}

// ---------------------------------------------------------------------------
// gemmG: 256x128 bf16 GEMM, 8 waves x (64x64 out), BK=64, single-buffer
// 48 KiB LDS, T2 swizzle (0-conflict class), plain block order.
// (r10 best-measured config for QKV / MLP1.)
// MODE 3: bf16 = tanh-gelu(v+bias) | MODE 5: QKV split (QK bf16 / Vt store)
// ---------------------------------------------------------------------------
template<int MODE>
__global__ __launch_bounds__(512, 4)
void gemmG(const u16* __restrict__ A, const u16* __restrict__ Bt,
           void* __restrict__ Cv, const float* __restrict__ bias,
           u16* __restrict__ Vt, int M, int N, int K, int ldA, int ldB,
           float scale)
{
  __shared__ __align__(16) u16 As[256 * 64];   // 32 KiB
  __shared__ __align__(16) u16 Bs[128 * 64];   // 16 KiB

  const long m0 = (long)blockIdx.x * 256, n0 = (long)blockIdx.y * 128;
  const int t = threadIdx.x;
  const int wave = t >> 6, lane = t & 63;
  const int wr = (wave >> 1) * 64, wc = (wave & 1) * 64;   // 4(M) x 2(N)
  const int lg = lane >> 4, lr = lane & 15;

  const long ldA2 = (long)ldA * 2, ldB2 = (long)ldB * 2;

  const int rl = lane >> 3, c7 = lane & 7;
  const int sb = (c7 * 16) ^ (rl << 4);
  const char* aP[4]; const char* bP[2];
  u16* aL[4]; u16* bL[2];
  {
    const char* Ab = (const char*)A;
    const char* Bb = (const char*)Bt;
    #pragma unroll
    for (int c = 0; c < 4; ++c) {
      const int q = c * 8 + wave;
      aP[c] = Ab + (m0 + q * 8 + rl) * ldA2 + sb;
      aL[c] = As + q * 512;
    }
    #pragma unroll
    for (int c = 0; c < 2; ++c) {
      const int q = c * 8 + wave;
      bP[c] = Bb + (n0 + q * 8 + rl) * ldB2 + sb;
      bL[c] = Bs + q * 512;
    }
  }

  const int rswz = (lr & 7) << 4;
  auto rd = [&](const u16* base, int row, int cbyte) -> bf16x8 {
    return *reinterpret_cast<const bf16x8*>(
        reinterpret_cast<const char*>(base) + row * 128 + (cbyte ^ rswz));
  };

  f32x4 acc[4][4];
  #pragma unroll
  for (int i = 0; i < 4; ++i)
    #pragma unroll
    for (int j = 0; j < 4; ++j)
      acc[i][j] = (f32x4){0.f, 0.f, 0.f, 0.f};

  for (int k0 = 0; k0 < K; k0 += 64) {
    #pragma unroll
    for (int c = 0; c < 4; ++c) { gload16(aP[c], aL[c]); aP[c] += 128; }
    #pragma unroll
    for (int c = 0; c < 2; ++c) { gload16(bP[c], bL[c]); bP[c] += 128; }
    __syncthreads();

    #pragma unroll
    for (int ks = 0; ks < 2; ++ks) {
      bf16x8 a[4], b[4];
      #pragma unroll
      for (int i = 0; i < 4; ++i)
        a[i] = rd(As, wr + i * 16 + lr, ks * 64 + lg * 16);
      #pragma unroll
      for (int i = 0; i < 4; ++i)
        b[i] = rd(Bs, wc + i * 16 + lr, ks * 64 + lg * 16);
      #pragma unroll
      for (int mi = 0; mi < 4; ++mi)
        #pragma unroll
        for (int ni = 0; ni < 4; ++ni)
          acc[mi][ni] = __builtin_amdgcn_mfma_f32_16x16x32_bf16(a[mi], b[ni], acc[mi][ni], 0, 0, 0);
    }
    __syncthreads();
  }

  #pragma unroll
  for (int mi = 0; mi < 4; ++mi) {
    #pragma unroll
    for (int ni = 0; ni < 4; ++ni) {
      #pragma unroll
      for (int r = 0; r < 4; ++r) {
        const long grow = m0 + wr + mi * 16 + lg * 4 + r;
        const long gcol = n0 + wc + ni * 16 + lr;
        const float v = acc[mi][ni][r];
        if constexpr (MODE == 3) {
          const float x = v + bias[gcol];
          const float u2 = 1.59576912f * x * (1.f + 0.044715f * x * x);
          const float ge = x / (1.f + __expf(-u2));
          ((u16*)Cv)[grow * N + gcol] = f2bf(ge);
        } else if constexpr (MODE == 5) {
          if (gcol < 2048) {
            ((u16*)Cv)[grow * 2048 + gcol] = f2bf(v * scale);
          } else {
            const long b = grow >> 10, tk = grow & 1023, d = gcol - 2048;
            Vt[(b << 20) + (d << 10) + tk] = f2bf(v);
          }
        }
      }
    }
  }
}

// ---------------------------------------------------------------------------
// gemm8: 8-wave 128x128, BK=64, single-buffer 32 KiB (high-TLP config).
// MODE 4: f32 += v + bias
// ---------------------------------------------------------------------------
template<int MODE>
__global__ __launch_bounds__(512, 4)
void gemm8(const u16* __restrict__ A, const u16* __restrict__ Bt,
           void* __restrict__ Cv, const float* __restrict__ bias,
           u16* __restrict__ Vt, int M, int N, int K, int ldA, int ldB,
           float scale)
{
  __shared__ __align__(16) u16 As[128 * 64];
  __shared__ __align__(16) u16 Bs[128 * 64];

  const long m0 = (long)blockIdx.x * 128, n0 = (long)blockIdx.y * 128;
  const int t = threadIdx.x;
  const int wave = t >> 6, lane = t & 63;
  const int wr = (wave >> 2) * 64, wc = (wave & 3) * 32;
  const int lg = lane >> 4, lr = lane & 15;

  const long ldA2 = (long)ldA * 2, ldB2 = (long)ldB * 2;

  const int rl = lane >> 3, c7 = lane & 7;
  const int sb = (c7 * 16) ^ (rl << 4);
  const char* aP[2]; const char* bP[2];
  u16* aL[2]; u16* bL[2];
  {
    const char* Ab = (const char*)A;
    const char* Bb = (const char*)Bt;
    #pragma unroll
    for (int c = 0; c < 2; ++c) {
      const int q = c * 8 + wave;
      aP[c] = Ab + (m0 + q * 8 + rl) * ldA2 + sb;
      bP[c] = Bb + (n0 + q * 8 + rl) * ldB2 + sb;
      aL[c] = As + q * 512;
      bL[c] = Bs + q * 512;
    }
  }

  const int rswz = (lr & 7) << 4;
  auto rd = [&](const u16* base, int row, int cbyte) -> bf16x8 {
    return *reinterpret_cast<const bf16x8*>(
        reinterpret_cast<const char*>(base) + row * 128 + (cbyte ^ rswz));
  };

  f32x4 acc[4][2];
  #pragma unroll
  for (int i = 0; i < 4; ++i)
    #pragma unroll
    for (int j = 0; j < 2; ++j)
      acc[i][j] = (f32x4){0.f, 0.f, 0.f, 0.f};

  for (int k0 = 0; k0 < K; k0 += 64) {
    #pragma unroll
    for (int c = 0; c < 2; ++c) {
      gload16(aP[c], aL[c]);
      gload16(bP[c], bL[c]);
      aP[c] += 128; bP[c] += 128;
    }
    __syncthreads();

    #pragma unroll
    for (int ks = 0; ks < 2; ++ks) {
      bf16x8 a[4], b[2];
      #pragma unroll
      for (int i = 0; i < 4; ++i)
        a[i] = rd(As, wr + i * 16 + lr, ks * 64 + lg * 16);
      #pragma unroll
      for (int i = 0; i < 2; ++i)
        b[i] = rd(Bs, wc + i * 16 + lr, ks * 64 + lg * 16);
      #pragma unroll
      for (int mi = 0; mi < 4; ++mi)
        #pragma unroll
        for (int ni = 0; ni < 2; ++ni)
          acc[mi][ni] = __builtin_amdgcn_mfma_f32_16x16x32_bf16(a[mi], b[ni], acc[mi][ni], 0, 0, 0);
    }
    __syncthreads();
  }

  #pragma unroll
  for (int mi = 0; mi < 4; ++mi) {
    #pragma unroll
    for (int ni = 0; ni < 2; ++ni) {
      #pragma unroll
      for (int r = 0; r < 4; ++r) {
        const long grow = m0 + wr + mi * 16 + lg * 4 + r;
        const long gcol = n0 + wc + ni * 16 + lr;
        const float v = acc[mi][ni][r];
        if constexpr (MODE == 4) {
          float* Cp = (float*)Cv;
          const long idx = grow * N + gcol;
          Cp[idx] = Cp[idx] + v + bias[gcol];
        }
      }
    }
  }
}

// ---------------------------------------------------------------------------
// gemm8b: batched 8-wave 128x128, BK=64, single-buffer (S and PV).
// MODE 0: bf16 = v*scale | MODE 2: f32 +=
// ---------------------------------------------------------------------------
template<int MODE>
__global__ __launch_bounds__(512, 4)
void gemm8b(const u16* __restrict__ A, const u16* __restrict__ Bt,
            void* __restrict__ Cv, int N, int K, int ldA, int ldB,
            long sA, long sB, long sC, float scale)
{
  __shared__ __align__(16) u16 As[128 * 64];
  __shared__ __align__(16) u16 Bs[128 * 64];

  const int bz = blockIdx.z;
  const long m0 = (long)blockIdx.x * 128, n0 = (long)blockIdx.y * 128;
  const int t = threadIdx.x;
  const int wave = t >> 6, lane = t & 63;
  const int wr = (wave >> 2) * 64, wc = (wave & 3) * 32;
  const int lg = lane >> 4, lr = lane & 15;

  const long ldA2 = (long)ldA * 2, ldB2 = (long)ldB * 2;

  const int rl = lane >> 3, c7 = lane & 7;
  const int sb = (c7 * 16) ^ (rl << 4);
  const char* aP[2]; const char* bP[2];
  u16* aL[2]; u16* bL[2];
  {
    const char* Ab = (const char*)(A + (long)bz * sA);
    const char* Bb = (const char*)(Bt + (long)bz * sB);
    #pragma unroll
    for (int c = 0; c < 2; ++c) {
      const int q = c * 8 + wave;
      aP[c] = Ab + (m0 + q * 8 + rl) * ldA2 + sb;
      bP[c] = Bb + (n0 + q * 8 + rl) * ldB2 + sb;
      aL[c] = As + q * 512;
      bL[c] = Bs + q * 512;
    }
  }

  const int rswz = (lr & 7) << 4;
  auto rd = [&](const u16* base, int row, int cbyte) -> bf16x8 {
    return *reinterpret_cast<const bf16x8*>(
        reinterpret_cast<const char*>(base) + row * 128 + (cbyte ^ rswz));
  };

  f32x4 acc[4][2];
  #pragma unroll
  for (int i = 0; i < 4; ++i)
    #pragma unroll
    for (int j = 0; j < 2; ++j)
      acc[i][j] = (f32x4){0.f, 0.f, 0.f, 0.f};

  for (int k0 = 0; k0 < K; k0 += 64) {
    #pragma unroll
    for (int c = 0; c < 2; ++c) {
      gload16(aP[c], aL[c]);
      gload16(bP[c], bL[c]);
      aP[c] += 128; bP[c] += 128;
    }
    __syncthreads();

    #pragma unroll
    for (int ks = 0; ks < 2; ++ks) {
      bf16x8 a[4], b[2];
      #pragma unroll
      for (int i = 0; i < 4; ++i)
        a[i] = rd(As, wr + i * 16 + lr, ks * 64 + lg * 16);
      #pragma unroll
      for (int i = 0; i < 2; ++i)
        b[i] = rd(Bs, wc + i * 16 + lr, ks * 64 + lg * 16);
      #pragma unroll
      for (int mi = 0; mi < 4; ++mi)
        #pragma unroll
        for (int ni = 0; ni < 2; ++ni)
          acc[mi][ni] = __builtin_amdgcn_mfma_f32_16x16x32_bf16(a[mi], b[ni], acc[mi][ni], 0, 0, 0);
    }
    __syncthreads();
  }

  #pragma unroll
  for (int mi = 0; mi < 4; ++mi) {
    #pragma unroll
    for (int ni = 0; ni < 2; ++ni) {
      #pragma unroll
      for (int r = 0; r < 4; ++r) {
        const long grow = m0 + wr + mi * 16 + lg * 4 + r;
        const long gcol = n0 + wc + ni * 16 + lr;
        const float v = acc[mi][ni][r];
        if constexpr (MODE == 0) {
          u16* Cp = (u16*)Cv + (long)bz * sC;
          Cp[grow * N + gcol] = f2bf(v * scale);
        } else if constexpr (MODE == 2) {
          float* Cp = (float*)Cv + (long)bz * sC;
          Cp[grow * N + gcol] += v;
        }
      }
    }
  }
}

// ---------------------------------------------------------------------------
// Per-layer weight transpose+convert: f32 [K][N] -> bf16 [N][K].
// LDS pad = 70 u16 = 35 dwords (ODD) -> column-read spreads over 16 banks
// with same-word lane pairs (broadcast) => effective 2-way = free.
// (r12's 68-pad was ~8-way conflicted: 1.3e7 conflicts measured.)
// Per-layer launches keep the 22 MB output L2/L3-hot for the GEMMs
// (r12's all-layer batch evicted it: +471 us).
// Outputs contiguous: WqT+0, WkT+1M, WvT+2M (=> QKV concat [3072][1024]),
// W1T+3M, W2T+7M (u16 elements).
// ---------------------------------------------------------------------------
__global__ __launch_bounds__(256)
void trans_k(const float* __restrict__ wq, const float* __restrict__ wk,
             const float* __restrict__ wv, const float* __restrict__ w1,
             const float* __restrict__ w2, u16* __restrict__ ob)
{
  __shared__ u16 T[64][70];
  const int b = blockIdx.x;
  const float* in; u16* out; int K, N, tk, tn;
  if (b < 768) {
    const int m = b >> 8, tt = b & 255;
    in = (m == 0) ? wq : (m == 1) ? wk : wv;
    out = ob + (long)m * 1048576L;
    K = 1024; N = 1024; tk = tt >> 4; tn = tt & 15;
  } else if (b < 1792) {
    const int tt = b - 768;
    in = w1; out = ob + 3L * 1048576L; K = 1024; N = 4096;
    tk = tt >> 6; tn = tt & 63;
  } else {
    const int tt = b - 1792;
    in = w2; out = ob + 7L * 1048576L; K = 4096; N = 1024;
    tk = tt >> 4; tn = tt & 15;
  }
  const int k0 = tk * 64, n0 = tn * 64;
  const int t = threadIdx.x;
  {
    const int r = t >> 2, cq = (t & 3) * 16;
    const float* src = in + (long)(k0 + r) * N + n0 + cq;
    #pragma unroll
    for (int q = 0; q < 4; ++q) {
      const float4 v = *reinterpret_cast<const float4*>(src + q * 4);
      T[r][cq + q * 4 + 0] = f2bf(v.x);
      T[r][cq + q * 4 + 1] = f2bf(v.y);
      T[r][cq + q * 4 + 2] = f2bf(v.z);
      T[r][cq + q * 4 + 3] = f2bf(v.w);
    }
  }
  __syncthreads();
  {
    const int n = t >> 2, kq2 = (t & 3) * 16;
    u16 tmp[16];
    #pragma unroll
    for (int j = 0; j < 16; ++j) tmp[j] = T[kq2 + j][n];
    uint4* dst = reinterpret_cast<uint4*>(out + (long)(n0 + n) * K + k0 + kq2);
    dst[0] = *reinterpret_cast<const uint4*>(&tmp[0]);
    dst[1] = *reinterpret_cast<const uint4*>(&tmp[8]);
  }
}

// ---------------------------------------------------------------------------
__global__ __launch_bounds__(256)
void embed_k(const int* __restrict__ xt, const int* __restrict__ zi,
             const float* __restrict__ pos, const float* __restrict__ temb,
             float* __restrict__ H)
{
  const int bt = blockIdx.x;
  const int b = bt >> 10, tk = bt & 1023;
  const int d = threadIdx.x * 4;
  const float4 p = reinterpret_cast<const float4*>(pos + (long)tk * 1024)[threadIdx.x];
  float4 v;
  if (tk < 512) {
    const float z = (float)zi[b * 512 + tk];
    const float c0 = (float)(d + 0) - z, c1 = (float)(d + 1) - z;
    const float c2 = (float)(d + 2) - z, c3 = (float)(d + 3) - z;
    v.x = (d + 0 < 10) ? -0.5f * c0 * c0 : 0.f;
    v.y = (d + 1 < 10) ? -0.5f * c1 * c1 : 0.f;
    v.z = (d + 2 < 10) ? -0.5f * c2 * c2 : 0.f;
    v.w = (d + 3 < 10) ? -0.5f * c3 * c3 : 0.f;
  } else {
    const float* te = temb + (long)xt[b * 512 + (tk - 512)] * 1024;
    v = reinterpret_cast<const float4*>(te)[threadIdx.x];
  }
  float4 o; o.x = v.x + p.x; o.y = v.y + p.y; o.z = v.z + p.z; o.w = v.w + p.w;
  reinterpret_cast<float4*>(H + (long)bt * 1024)[threadIdx.x] = o;
}

__global__ __launch_bounds__(256)
void ln_k(const float* __restrict__ X, const float* __restrict__ g,
          const float* __restrict__ bta, u16* __restrict__ Y)
{
  __shared__ float sm[8];
  const long row = blockIdx.x;
  const float4 x = reinterpret_cast<const float4*>(X + row * 1024)[threadIdx.x];
  float s1 = x.x + x.y + x.z + x.w;
  float s2 = x.x * x.x + x.y * x.y + x.z * x.z + x.w * x.w;
  #pragma unroll
  for (int o = 32; o > 0; o >>= 1) { s1 += __shfl_down(s1, o); s2 += __shfl_down(s2, o); }
  const int w = threadIdx.x >> 6, ln = threadIdx.x & 63;
  if (ln == 0) { sm[w] = s1; sm[4 + w] = s2; }
  __syncthreads();
  s1 = sm[0] + sm[1] + sm[2] + sm[3];
  s2 = sm[4] + sm[5] + sm[6] + sm[7];
  const float mu = s1 * (1.f / 1024.f);
  const float var = s2 * (1.f / 1024.f) - mu * mu;
  const float inv = rsqrtf(var + 1e-5f);
  const float4 gg = reinterpret_cast<const float4*>(g)[threadIdx.x];
  const float4 bb = reinterpret_cast<const float4*>(bta)[threadIdx.x];
  const u32 o0 = (u32)f2bf((x.x - mu) * inv * gg.x + bb.x) | ((u32)f2bf((x.y - mu) * inv * gg.y + bb.y) << 16);
  const u32 o1 = (u32)f2bf((x.z - mu) * inv * gg.z + bb.z) | ((u32)f2bf((x.w - mu) * inv * gg.w + bb.w) << 16);
  reinterpret_cast<uint2*>(Y + row * 1024)[threadIdx.x] = make_uint2(o0, o1);
}

// Row softmax over 1024 cols, bf16 in -> bf16 out
__global__ __launch_bounds__(256)
void sm_k(const u16* __restrict__ S, u16* __restrict__ P)
{
  __shared__ float sm[8];
  const long row = blockIdx.x;
  const uint2 raw = reinterpret_cast<const uint2*>(S + row * 1024)[threadIdx.x];
  const float x0 = bf2f(raw.x & 0xffffu), x1 = bf2f(raw.x >> 16);
  const float x2 = bf2f(raw.y & 0xffffu), x3 = bf2f(raw.y >> 16);
  float m = fmaxf(fmaxf(x0, x1), fmaxf(x2, x3));
  #pragma unroll
  for (int o = 32; o > 0; o >>= 1) m = fmaxf(m, __shfl_down(m, o));
  const int w = threadIdx.x >> 6, ln = threadIdx.x & 63;
  if (ln == 0) sm[w] = m;
  __syncthreads();
  m = fmaxf(fmaxf(sm[0], sm[1]), fmaxf(sm[2], sm[3]));
  const float e0 = __expf(x0 - m), e1 = __expf(x1 - m);
  const float e2 = __expf(x2 - m), e3 = __expf(x3 - m);
  float s = e0 + e1 + e2 + e3;
  #pragma unroll
  for (int o = 32; o > 0; o >>= 1) s += __shfl_down(s, o);
  if (ln == 0) sm[4 + w] = s;
  __syncthreads();
  const float tot = sm[4] + sm[5] + sm[6] + sm[7];
  const float r = 1.0f / tot;
  const u32 o0 = (u32)f2bf(e0 * r) | ((u32)f2bf(e1 * r) << 16);
  const u32 o1 = (u32)f2bf(e2 * r) | ((u32)f2bf(e3 * r) << 16);
  reinterpret_cast<uint2*>(P + row * 1024)[threadIdx.x] = make_uint2(o0, o1);
}

__global__ __launch_bounds__(256)
void ro_k(const float* __restrict__ H, const float* __restrict__ w,
          const float* __restrict__ b, float* __restrict__ out)
{
  __shared__ float sm[4];
  const int row = blockIdx.x;
  const int bb = row >> 9, i = row & 511;
  const float* h = H + ((long)bb * 1024 + i) * 1024;
  const float4 x = reinterpret_cast<const float4*>(h)[threadIdx.x];
  const float4 ww = reinterpret_cast<const float4*>(w)[threadIdx.x];
  float s = x.x * ww.x + x.y * ww.y + x.z * ww.z + x.w * ww.w;
  #pragma unroll
  for (int o = 32; o > 0; o >>= 1) s += __shfl_down(s, o);
  const int wv = threadIdx.x >> 6, ln = threadIdx.x & 63;
  if (ln == 0) sm[wv] = s;
  __syncthreads();
  if (threadIdx.x == 0) out[row] = sm[0] + sm[1] + sm[2] + sm[3] + b[0];
}

// ---------------------------------------------------------------------------
extern "C" void kernel_launch(void* const* d_in, const int* in_sizes, int n_in,
                              void* d_out, int out_size, void* d_ws, size_t ws_size,
                              hipStream_t stream)
{
  const int* xt = (const int*)d_in[0];
  const int* zi = (const int*)d_in[1];
  const float* pos  = (const float*)d_in[2];
  const float* temb = (const float*)d_in[3];
  const float* Wq = (const float*)d_in[4];
  const float* Wk = (const float*)d_in[5];
  const float* Wv = (const float*)d_in[6];
  const float* ln1g = (const float*)d_in[7];
  const float* ln1b = (const float*)d_in[8];
  const float* ln2g = (const float*)d_in[9];
  const float* ln2b = (const float*)d_in[10];
  const float* w1 = (const float*)d_in[11];
  const float* b1 = (const float*)d_in[12];
  const float* w2 = (const float*)d_in[13];
  const float* b2 = (const float*)d_in[14];
  const float* row_w = (const float*)d_in[15];
  const float* row_b = (const float*)d_in[16];

  char* ws = (char*)d_ws;
  const long MB = 1024 * 1024;
  float* H   = (float*)(ws + 0);          // 32 MB  [8][1024][1024] f32
  u16*   H1  = (u16*)(ws + 32 * MB);      // 16 MB  [8192][1024] bf16
  u16*   QK  = (u16*)(ws + 48 * MB);      // 32 MB  [8192][2048] bf16 (Q||K)
  u16*   Vt  = (u16*)(ws + 80 * MB);      // 16 MB  [8][1024(d)][1024(t)]
  u16*   S   = (u16*)(ws + 96 * MB);      // 16 MB  bf16
  u16*   P   = (u16*)(ws + 112 * MB);     // 16 MB
  u16*   G   = (u16*)(ws + 80 * MB);      // 64 MB, aliases Vt/S/P (dead in MLP)
  u16*   WT  = (u16*)(ws + 144 * MB);     // 22 MB  per-layer bf16 weights (B^T)

  u16* W1T = WT + 3 * 1048576L;           // [4096][1024]
  u16* W2T = WT + 7 * 1048576L;           // [1024][4096]

  const long s1M = 1024L * 1024L;
  const long s2M = 2L * 1024L * 1024L;

  embed_k<<<8192, 256, 0, stream>>>(xt, zi, pos, temb, H);

  for (int l = 0; l < 12; ++l) {
    const float* wq = Wq + (long)l * s1M;
    const float* wk = Wk + (long)l * s1M;
    const float* wv = Wv + (long)l * s1M;
    const float* mw1 = w1 + (long)l * 1024L * 4096L;
    const float* mb1 = b1 + (long)l * 4096L;
    const float* mw2 = w2 + (long)l * 4096L * 1024L;
    const float* mb2 = b2 + (long)l * 1024L;

    trans_k<<<2816, 256, 0, stream>>>(wq, wk, wv, mw1, mw2, WT);

    ln_k<<<8192, 256, 0, stream>>>(H, ln1g + l * 1024, ln1b + l * 1024, H1);

    // [Q||K||V] = H1 @ [wq||wk||wv]; V third stored transposed into Vt
    gemmG<5><<<dim3(32, 24, 1), 512, 0, stream>>>(H1, WT, QK, nullptr, Vt,
        8192, 3072, 1024, 1024, 1024, 1.f);

    // S = Q @ K^T / 32
    gemm8b<0><<<dim3(8, 8, 8), 512, 0, stream>>>(QK, QK + 1024, S,
        1024, 1024, 2048, 2048, s2M, s2M, s1M, 1.f / 32.f);

    sm_k<<<8192, 256, 0, stream>>>(S, P);

    // H += P @ V
    gemm8b<2><<<dim3(8, 8, 8), 512, 0, stream>>>(P, Vt, (void*)H,
        1024, 1024, 1024, 1024, s1M, s1M, s1M, 1.f);

    ln_k<<<8192, 256, 0, stream>>>(H, ln2g + l * 1024, ln2b + l * 1024, H1);

    // G = gelu(H1 @ w1 + b1)
    gemmG<3><<<dim3(32, 32, 1), 512, 0, stream>>>(H1, W1T, G, mb1, nullptr,
        8192, 4096, 1024, 1024, 1024, 1.f);
    // H += G @ w2 + b2
    gemm8<4><<<dim3(64, 8, 1), 512, 0, stream>>>(G, W2T, (void*)H, mb2, nullptr,
        8192, 1024, 4096, 4096, 4096, 1.f);
  }

  ro_k<<<4096, 256, 0, stream>>>(H, row_w, row_b, (float*)d_out);
}